// Round 4
// baseline (569.072 us; speedup 1.0000x reference)
//
#include <hip/hip_runtime.h>

#define L_    2048
#define DIM_  3072
#define H_    24
#define D_    128
#define NQKV  9216   // 3*DIM

typedef __attribute__((ext_vector_type(8))) short bf16x8;   // 8 bf16 = 4 VGPRs
typedef __attribute__((ext_vector_type(4))) short bf16x4;   // 4 bf16 = 2 VGPRs
typedef __attribute__((ext_vector_type(4))) float f32x4;

__device__ __forceinline__ unsigned short f2bf(float f) {
  union { float f; unsigned u; } v; v.f = f;
  unsigned r = v.u + 0x7fffu + ((v.u >> 16) & 1u);   // RNE
  return (unsigned short)(r >> 16);
}

// async global->LDS, 16B per lane. LDS dest = wave-uniform base + lane*16.
__device__ __forceinline__ void gload_lds16(const void* g, void* l) {
  auto* lp = reinterpret_cast<__attribute__((address_space(3))) unsigned int*>(
      reinterpret_cast<uintptr_t>(l));
  auto* gp = reinterpret_cast<const __attribute__((address_space(1))) unsigned int*>(
      reinterpret_cast<uintptr_t>(g));
  __builtin_amdgcn_global_load_lds(gp, lp, 16, 0, 0);
}

// ---------------------------------------------------------------- cast fp32->bf16
__global__ void cast_f32_to_bf16(const float* __restrict__ in,
                                 unsigned short* __restrict__ out, int n) {
  int total = n >> 2;
  int stride = gridDim.x * blockDim.x;
  for (int i = blockIdx.x * blockDim.x + threadIdx.x; i < total; i += stride) {
    float4 v = ((const float4*)in)[i];
    ushort4 o;
    o.x = f2bf(v.x); o.y = f2bf(v.y); o.z = f2bf(v.z); o.w = f2bf(v.w);
    ((ushort4*)out)[i] = o;
  }
}

// ---------------------------------------------------------------- cast + transpose
// in[K][N] fp32 -> out[N][K] bf16.  Lane along k => coalesced writes; float4
// streaming loads per lane (L1 catches the strided lines).
__global__ __launch_bounds__(256)
void castT_f32_bf16(const float* __restrict__ in, unsigned short* __restrict__ out,
                    int K, int N) {
  int k = blockIdx.x * 256 + threadIdx.x;
  int n0 = blockIdx.y * 128;
  const float* src = in + (size_t)k * N + n0;
  #pragma unroll 4
  for (int j4 = 0; j4 < 32; j4++) {
    float4 v = *(const float4*)&src[j4 * 4];
    out[(size_t)(n0 + j4 * 4 + 0) * K + k] = f2bf(v.x);
    out[(size_t)(n0 + j4 * 4 + 1) * K + k] = f2bf(v.y);
    out[(size_t)(n0 + j4 * 4 + 2) * K + k] = f2bf(v.z);
    out[(size_t)(n0 + j4 * 4 + 3) * K + k] = f2bf(v.w);
  }
}

// ---------------------------------------------------------------- QKV GEMM + RMS/RoPE
// qkv[M][9216] = x[M][3072] * w_qkvT[9216][3072]^T.  128x128 tile => each block's
// C-tile is one (type,head) x 128 seq rows.  q/k blocks: RMSNorm over d (tile
// cols) + RoPE fused on fp32 accs, write [H][L][D].  v blocks: write v_buf.
__global__ __launch_bounds__(256, 3)
void gemm_qkv(const unsigned short* __restrict__ A,
              const unsigned short* __restrict__ Bt,
              const float* __restrict__ pe,        // [L][64][2][2]
              const float* __restrict__ q_scale,
              const float* __restrict__ k_scale,
              unsigned short* __restrict__ Qo,     // [H][L][D]
              unsigned short* __restrict__ Ko,     // [H][L][D]
              unsigned short* __restrict__ Vo)     // [L][DIM]
{
  const int M = L_, N = NQKV, K = DIM_;
  __shared__ unsigned short As[128 * 64];
  __shared__ unsigned short Bs[128 * 64];
  const int tid  = threadIdx.x;
  const int wave = tid >> 6;
  const int lane = tid & 63;
  const int l15  = lane & 15;
  const int quad = lane >> 4;
  const int wm = wave >> 1, wn = wave & 1;
  const int bm = blockIdx.y * 128;
  const int bn = blockIdx.x * 128;

  const int srow = lane >> 3;
  const int scol = (lane & 7) ^ srow;
  const unsigned short* Ag = A  + (size_t)(bm + wave * 32 + srow) * K + scol * 8;
  const unsigned short* Bg = Bt + (size_t)(bn + wave * 32 + srow) * K + scol * 8;
  unsigned short* Al = &As[(wave * 32) * 64];
  unsigned short* Bl = &Bs[(wave * 32) * 64];

  f32x4 acc[4][4];
  #pragma unroll
  for (int i = 0; i < 4; i++)
    #pragma unroll
    for (int j = 0; j < 4; j++) acc[i][j] = (f32x4){0.f, 0.f, 0.f, 0.f};

  for (int k0 = 0; k0 < K; k0 += 64) {
    __syncthreads();
    #pragma unroll
    for (int j = 0; j < 4; j++) {
      gload_lds16(Ag + (size_t)j * 8 * K + k0, Al + j * 8 * 64);
      gload_lds16(Bg + (size_t)j * 8 * K + k0, Bl + j * 8 * 64);
    }
    __syncthreads();
    #pragma unroll
    for (int ks = 0; ks < 2; ks++) {
      const int cph = ((ks * 4 + quad) ^ (l15 & 7)) * 8;
      bf16x8 af[4], bf[4];
      #pragma unroll
      for (int mt = 0; mt < 4; mt++)
        af[mt] = *(const bf16x8*)&As[(wm * 64 + mt * 16 + l15) * 64 + cph];
      #pragma unroll
      for (int nt = 0; nt < 4; nt++)
        bf[nt] = *(const bf16x8*)&Bs[(wn * 64 + nt * 16 + l15) * 64 + cph];
      #pragma unroll
      for (int mt = 0; mt < 4; mt++)
        #pragma unroll
        for (int nt = 0; nt < 4; nt++)
          acc[mt][nt] = __builtin_amdgcn_mfma_f32_16x16x32_bf16(
              af[mt], bf[nt], acc[mt][nt], 0, 0, 0);
    }
  }
  __syncthreads();   // all waves done with As/Bs; safe to reuse As as rbuf

  const int bnx = blockIdx.x;
  if (bnx < 48) {
    // ---- q or k head: RMSNorm + RoPE on fp32 accumulators
    const bool isQ = bnx < 24;
    const int  hh  = isQ ? bnx : bnx - 24;
    const float* sc = isQ ? q_scale : k_scale;
    unsigned short* dst = isQ ? Qo : Ko;
    float* rbuf = (float*)As;                     // [2][128] partial sumsq
    #pragma unroll
    for (int mt = 0; mt < 4; mt++)
      #pragma unroll
      for (int r = 0; r < 4; r++) {
        float p = 0.f;
        #pragma unroll
        for (int nt = 0; nt < 4; nt++) p += acc[mt][nt][r] * acc[mt][nt][r];
        p += __shfl_xor(p, 1); p += __shfl_xor(p, 2);
        p += __shfl_xor(p, 4); p += __shfl_xor(p, 8);
        if (l15 == 0) rbuf[wn * 128 + wm * 64 + mt * 16 + quad * 4 + r] = p;
      }
    __syncthreads();
    #pragma unroll
    for (int mt = 0; mt < 4; mt++)
      #pragma unroll
      for (int r = 0; r < 4; r++) {
        const int lrow = wm * 64 + mt * 16 + quad * 4 + r;
        const int lg = bm + lrow;
        float ms = (rbuf[lrow] + rbuf[128 + lrow]) * (1.f / 128.f);
        float rinv = rsqrtf(ms + 1e-6f);
        #pragma unroll
        for (int nt = 0; nt < 4; nt++) {
          const int d = wn * 64 + nt * 16 + l15;
          float n  = acc[mt][nt][r] * rinv * sc[d];
          float np = __shfl_xor(n, 1);
          float2 ab = *(const float2*)&pe[(size_t)lg * 256 + (d >> 1) * 4 + (d & 1) * 2];
          float xe = (d & 1) ? np : n;
          float xo = (d & 1) ? n  : np;
          float o = ab.x * xe + ab.y * xo;
          if (isQ) o *= 0.08838834764831845f;     // 1/sqrt(128)
          dst[((size_t)hh * L_ + lg) * D_ + d] = f2bf(o);
        }
      }
  } else {
    // ---- v head: plain write to v_buf[L][DIM]
    const int hh = bnx - 48;
    #pragma unroll
    for (int mt = 0; mt < 4; mt++)
      #pragma unroll
      for (int nt = 0; nt < 4; nt++)
        #pragma unroll
        for (int r = 0; r < 4; r++) {
          int row = bm + wm * 64 + mt * 16 + quad * 4 + r;
          int col = hh * D_ + wn * 64 + nt * 16 + l15;
          Vo[(size_t)row * DIM_ + col] = f2bf(acc[mt][nt][r]);
        }
  }
}

// ---------------------------------------------------------------- bf16 MFMA GEMM (proj)
template<bool OUT_BF16, bool BIAS>
__global__ __launch_bounds__(256, 3)
void gemm_bt(const unsigned short* __restrict__ A,
             const unsigned short* __restrict__ Bt,
             void* __restrict__ Cout, const float* __restrict__ bias,
             int M, int N, int K)
{
  __shared__ unsigned short As[128 * 64];
  __shared__ unsigned short Bs[128 * 64];
  const int tid  = threadIdx.x;
  const int wave = tid >> 6;
  const int lane = tid & 63;
  const int l15  = lane & 15;
  const int quad = lane >> 4;
  const int wm = wave >> 1, wn = wave & 1;
  const int bm = blockIdx.y * 128;
  const int bn = blockIdx.x * 128;

  const int srow = lane >> 3;
  const int scol = (lane & 7) ^ srow;
  const unsigned short* Ag = A  + (size_t)(bm + wave * 32 + srow) * K + scol * 8;
  const unsigned short* Bg = Bt + (size_t)(bn + wave * 32 + srow) * K + scol * 8;
  unsigned short* Al = &As[(wave * 32) * 64];
  unsigned short* Bl = &Bs[(wave * 32) * 64];

  f32x4 acc[4][4];
  #pragma unroll
  for (int i = 0; i < 4; i++)
    #pragma unroll
    for (int j = 0; j < 4; j++) acc[i][j] = (f32x4){0.f, 0.f, 0.f, 0.f};

  for (int k0 = 0; k0 < K; k0 += 64) {
    __syncthreads();
    #pragma unroll
    for (int j = 0; j < 4; j++) {
      gload_lds16(Ag + (size_t)j * 8 * K + k0, Al + j * 8 * 64);
      gload_lds16(Bg + (size_t)j * 8 * K + k0, Bl + j * 8 * 64);
    }
    __syncthreads();
    #pragma unroll
    for (int ks = 0; ks < 2; ks++) {
      const int cph = ((ks * 4 + quad) ^ (l15 & 7)) * 8;
      bf16x8 af[4], bf[4];
      #pragma unroll
      for (int mt = 0; mt < 4; mt++)
        af[mt] = *(const bf16x8*)&As[(wm * 64 + mt * 16 + l15) * 64 + cph];
      #pragma unroll
      for (int nt = 0; nt < 4; nt++)
        bf[nt] = *(const bf16x8*)&Bs[(wn * 64 + nt * 16 + l15) * 64 + cph];
      #pragma unroll
      for (int mt = 0; mt < 4; mt++)
        #pragma unroll
        for (int nt = 0; nt < 4; nt++)
          acc[mt][nt] = __builtin_amdgcn_mfma_f32_16x16x32_bf16(
              af[mt], bf[nt], acc[mt][nt], 0, 0, 0);
    }
  }
  #pragma unroll
  for (int mt = 0; mt < 4; mt++)
    #pragma unroll
    for (int nt = 0; nt < 4; nt++)
      #pragma unroll
      for (int r = 0; r < 4; r++) {
        int row = bm + wm * 64 + mt * 16 + quad * 4 + r;
        int col = bn + wn * 64 + nt * 16 + l15;
        float v = acc[mt][nt][r];
        if (BIAS) v += bias[col];
        if (OUT_BF16)
          ((unsigned short*)Cout)[(size_t)row * N + col] = f2bf(v);
        else
          ((float*)Cout)[(size_t)row * N + col] = v;
      }
}

// ---------------------------------------------------------------- V transpose
// v_buf[l][h*128+d] -> Vt[h][d][l].  Lane = l: coalesced writes along Vt rows.
__global__ __launch_bounds__(256)
void v_transpose(const unsigned short* __restrict__ v_buf,
                 unsigned short* __restrict__ Vt) {
  int h = blockIdx.y;
  int l = blockIdx.x * 256 + threadIdx.x;
  const unsigned short* src = v_buf + (size_t)l * DIM_ + h * D_;
  unsigned short* dst = Vt + (size_t)h * D_ * L_ + l;
  #pragma unroll
  for (int c = 0; c < 16; c++) {
    uint4 v = *(const uint4*)&src[c * 8];
    const unsigned short* pv = (const unsigned short*)&v;
    #pragma unroll
    for (int j = 0; j < 8; j++)
      dst[(size_t)(c * 8 + j) * L_] = pv[j];
  }
}

// ---------------------------------------------------------------- flash attention
// Block: 4 waves, 64 queries, one head. Wave = (qg, kh): q-group of 32,
// key-half of the shared 64-key tile. S^T = K*Q^T so softmax is lane-indexed
// (q = l15) and P stays in registers as A-frags for mfma_16x16x16 PV.
__global__ __launch_bounds__(256, 3)
void flash_attn(const unsigned short* __restrict__ Q,   // [H][L][D]
                const unsigned short* __restrict__ K,   // [H][L][D]
                const unsigned short* __restrict__ Vt,  // [H][D][L]
                unsigned short* __restrict__ Out)       // [L][DIM]
{
  __shared__ __align__(16) char smem[34304];
  unsigned short* Ks = (unsigned short*)smem;          // [64][128] swizzled(16)
  unsigned short* Vs = Ks + 8192;                      // [128][64] swizzled(8)
  float*  Obuf = (float*)smem;                         // merge: [2][32][128]
  float2* mlb  = (float2*)(smem + 32768);              // [2*32]
  float4* sAr  = (float4*)(smem + 33280);              // [2*32]

  const int tid  = threadIdx.x;
  const int wave = tid >> 6;
  const int lane = tid & 63;
  const int l15  = lane & 15;
  const int quad = lane >> 4;
  const int qg = wave >> 1;
  const int kh = wave & 1;
  const int h  = blockIdx.y;
  const int q0 = blockIdx.x * 64 + qg * 32;

  const unsigned short* Qh = Q  + (size_t)h * L_ * D_;
  const unsigned short* Kh = K  + (size_t)h * L_ * D_;
  const unsigned short* Vh = Vt + (size_t)h * D_ * L_;

  bf16x8 qf[2][4];
  #pragma unroll
  for (int nt = 0; nt < 2; nt++)
    #pragma unroll
    for (int kc = 0; kc < 4; kc++)
      qf[nt][kc] = *(const bf16x8*)&Qh[(size_t)(q0 + nt * 16 + l15) * D_ + kc * 32 + quad * 8];

  f32x4 oacc[2][8];
  #pragma unroll
  for (int i = 0; i < 2; i++)
    #pragma unroll
    for (int j = 0; j < 8; j++) oacc[i][j] = (f32x4){0.f, 0.f, 0.f, 0.f};
  float m_i[2] = {-1e30f, -1e30f}, l_i[2] = {0.f, 0.f};

  const int kr_l = lane >> 4;
  const int vr_l = lane >> 3;
  const int vcl  = (lane & 7) ^ vr_l;

  for (int t = 0; t < L_; t += 64) {
    __syncthreads();
    #pragma unroll
    for (int ji = 0; ji < 4; ji++) {
      int Rr = wave * 16 + ji * 4;
      int cl = (lane & 15) ^ ((Rr + kr_l) & 15);
      gload_lds16(&Kh[(size_t)(t + Rr + kr_l) * D_ + cl * 8], &Ks[Rr * 128]);
      int R2 = wave * 32 + ji * 8;
      gload_lds16(&Vh[(size_t)(R2 + vr_l) * L_ + t + vcl * 8], &Vs[R2 * 64]);
    }
    __syncthreads();

    f32x4 s[2][2];
    #pragma unroll
    for (int i = 0; i < 2; i++)
      #pragma unroll
      for (int j = 0; j < 2; j++) s[i][j] = (f32x4){0.f, 0.f, 0.f, 0.f};
    #pragma unroll
    for (int mt = 0; mt < 2; mt++) {
      const int krow = kh * 32 + mt * 16 + l15;
      #pragma unroll
      for (int kc = 0; kc < 4; kc++) {
        bf16x8 kf = *(const bf16x8*)&Ks[krow * 128 + (((kc * 4 + quad) ^ l15) * 8)];
        s[mt][0] = __builtin_amdgcn_mfma_f32_16x16x32_bf16(kf, qf[0][kc], s[mt][0], 0, 0, 0);
        s[mt][1] = __builtin_amdgcn_mfma_f32_16x16x32_bf16(kf, qf[1][kc], s[mt][1], 0, 0, 0);
      }
    }
    float vmax[2], alpha[2], rs[2];
    #pragma unroll
    for (int nt = 0; nt < 2; nt++) {
      vmax[nt] = fmaxf(fmaxf(fmaxf(s[0][nt][0], s[0][nt][1]), fmaxf(s[0][nt][2], s[0][nt][3])),
                       fmaxf(fmaxf(s[1][nt][0], s[1][nt][1]), fmaxf(s[1][nt][2], s[1][nt][3])));
      vmax[nt] = fmaxf(vmax[nt], __shfl_xor(vmax[nt], 16));
      vmax[nt] = fmaxf(vmax[nt], __shfl_xor(vmax[nt], 32));
      float mnew = fmaxf(m_i[nt], vmax[nt]);
      alpha[nt] = __expf(m_i[nt] - mnew);
      m_i[nt] = mnew;
      rs[nt] = 0.f;
    }
    #pragma unroll
    for (int mt = 0; mt < 2; mt++)
      #pragma unroll
      for (int nt = 0; nt < 2; nt++)
        #pragma unroll
        for (int r = 0; r < 4; r++) {
          float p = __expf(s[mt][nt][r] - m_i[nt]);
          s[mt][nt][r] = p;
          rs[nt] += p;
        }
    #pragma unroll
    for (int nt = 0; nt < 2; nt++) {
      rs[nt] += __shfl_xor(rs[nt], 16);
      rs[nt] += __shfl_xor(rs[nt], 32);
      l_i[nt] = l_i[nt] * alpha[nt] + rs[nt];
    }
    float ar[2][4];
    #pragma unroll
    for (int qt = 0; qt < 2; qt++)
      #pragma unroll
      for (int r = 0; r < 4; r++)
        ar[qt][r] = __shfl(alpha[qt], quad * 4 + r);
    #pragma unroll
    for (int qt = 0; qt < 2; qt++)
      #pragma unroll
      for (int ntd = 0; ntd < 8; ntd++)
        #pragma unroll
        for (int r = 0; r < 4; r++)
          oacc[qt][ntd][r] *= ar[qt][r];
    bf16x4 pk[2][2];
    #pragma unroll
    for (int mt = 0; mt < 2; mt++)
      #pragma unroll
      for (int qt = 0; qt < 2; qt++)
        pk[mt][qt] = (bf16x4){(short)f2bf(s[mt][qt][0]), (short)f2bf(s[mt][qt][1]),
                              (short)f2bf(s[mt][qt][2]), (short)f2bf(s[mt][qt][3])};
    #pragma unroll
    for (int ntd = 0; ntd < 8; ntd++) {
      const int vrow = ntd * 16 + l15;
      #pragma unroll
      for (int mt = 0; mt < 2; mt++) {
        int phys = (kh * 4 + mt * 2 + (quad >> 1)) ^ (l15 & 7);
        bf16x4 vf = *(const bf16x4*)&Vs[vrow * 64 + phys * 8 + (quad & 1) * 4];
        oacc[0][ntd] = __builtin_amdgcn_mfma_f32_16x16x16bf16_1k(pk[mt][0], vf, oacc[0][ntd], 0, 0, 0);
        oacc[1][ntd] = __builtin_amdgcn_mfma_f32_16x16x16bf16_1k(pk[mt][1], vf, oacc[1][ntd], 0, 0, 0);
      }
    }
  }

  __syncthreads();
  if (kh == 1) {
    #pragma unroll
    for (int qt = 0; qt < 2; qt++)
      #pragma unroll
      for (int ntd = 0; ntd < 8; ntd++)
        #pragma unroll
        for (int r = 0; r < 4; r++)
          Obuf[(size_t)(qg * 32 + qt * 16 + quad * 4 + r) * 128 + ntd * 16 + l15] = oacc[qt][ntd][r];
    if (quad == 0)
      #pragma unroll
      for (int qt = 0; qt < 2; qt++)
        mlb[qg * 32 + qt * 16 + l15] = make_float2(m_i[qt], l_i[qt]);
  }
  __syncthreads();
  if (kh == 0 && quad == 0) {
    #pragma unroll
    for (int qt = 0; qt < 2; qt++) {
      float2 m1 = mlb[qg * 32 + qt * 16 + l15];
      float M  = fmaxf(m_i[qt], m1.x);
      float a0 = __expf(m_i[qt] - M);
      float a1 = __expf(m1.x - M);
      float Ls = l_i[qt] * a0 + m1.y * a1;
      sAr[qg * 32 + qt * 16 + l15] = make_float4(a0, a1, 1.f / Ls, 0.f);
    }
  }
  __syncthreads();
  if (kh == 0) {
    #pragma unroll
    for (int qt = 0; qt < 2; qt++)
      #pragma unroll
      for (int r = 0; r < 4; r++) {
        float4 A = sAr[qg * 32 + qt * 16 + quad * 4 + r];
        #pragma unroll
        for (int ntd = 0; ntd < 8; ntd++) {
          float o1 = Obuf[(size_t)(qg * 32 + qt * 16 + quad * 4 + r) * 128 + ntd * 16 + l15];
          float v  = (oacc[qt][ntd][r] * A.x + o1 * A.y) * A.z;
          Out[(size_t)(q0 + qt * 16 + quad * 4 + r) * DIM_ + h * D_ + ntd * 16 + l15] = f2bf(v);
        }
      }
  }
}

// ---------------------------------------------------------------- launcher
extern "C" void kernel_launch(void* const* d_in, const int* in_sizes, int n_in,
                              void* d_out, int out_size, void* d_ws, size_t ws_size,
                              hipStream_t stream) {
  const float* x       = (const float*)d_in[0];
  const float* pe      = (const float*)d_in[1];
  const float* w_qkv   = (const float*)d_in[2];
  const float* q_scale = (const float*)d_in[3];
  const float* k_scale = (const float*)d_in[4];
  const float* w_proj  = (const float*)d_in[5];
  const float* b_proj  = (const float*)d_in[6];

  unsigned short* w_qkvT  = (unsigned short*)d_ws;           // [9216][3072]
  unsigned short* w_projT = w_qkvT + 28311552;               // [3072][3072]
  unsigned short* x_b     = w_projT + 9437184;               // [2048][3072]
  unsigned short* v_buf   = x_b + 6291456;                   // [2048][3072]
  unsigned short* q_r     = v_buf + 6291456;                 // [H][L][D]
  unsigned short* k_r     = q_r + 6291456;
  unsigned short* vt_r    = k_r + 6291456;                   // [H][D][L]
  unsigned short* attn_b  = vt_r + 6291456;                  // [L][DIM]

  cast_f32_to_bf16<<<2048, 256, 0, stream>>>(x, x_b, 6291456);
  castT_f32_bf16<<<dim3(12, 72), 256, 0, stream>>>(w_qkv, w_qkvT, 3072, 9216);
  castT_f32_bf16<<<dim3(12, 24), 256, 0, stream>>>(w_proj, w_projT, 3072, 3072);

  gemm_qkv<<<dim3(72, 16), 256, 0, stream>>>(
      x_b, w_qkvT, pe, q_scale, k_scale, q_r, k_r, v_buf);

  v_transpose<<<dim3(8, 24), 256, 0, stream>>>(v_buf, vt_r);

  flash_attn<<<dim3(32, 24), 256, 0, stream>>>(q_r, k_r, vt_r, attn_b);

  gemm_bt<false, true><<<dim3(24, 16), 256, 0, stream>>>(
      attn_b, w_projT, d_out, b_proj, 2048, 3072, 3072);
}

// Round 5
// 552.193 us; speedup vs baseline: 1.0306x; 1.0306x over previous
//
#include <hip/hip_runtime.h>

#define L_    2048
#define DIM_  3072
#define H_    24
#define D_    128
#define NQKV  9216   // 3*DIM

typedef __attribute__((ext_vector_type(8))) short bf16x8;   // 8 bf16 = 4 VGPRs
typedef __attribute__((ext_vector_type(4))) short bf16x4;   // 4 bf16 = 2 VGPRs
typedef __attribute__((ext_vector_type(4))) float f32x4;

__device__ __forceinline__ unsigned short f2bf(float f) {
  union { float f; unsigned u; } v; v.f = f;
  unsigned r = v.u + 0x7fffu + ((v.u >> 16) & 1u);   // RNE
  return (unsigned short)(r >> 16);
}

// async global->LDS, 16B per lane. LDS dest = wave-uniform base + lane*16.
__device__ __forceinline__ void gload_lds16(const void* g, void* l) {
  auto* lp = reinterpret_cast<__attribute__((address_space(3))) unsigned int*>(
      reinterpret_cast<uintptr_t>(l));
  auto* gp = reinterpret_cast<const __attribute__((address_space(1))) unsigned int*>(
      reinterpret_cast<uintptr_t>(g));
  __builtin_amdgcn_global_load_lds(gp, lp, 16, 0, 0);
}

// ---------------------------------------------------------------- cast fp32->bf16
__global__ void cast_f32_to_bf16(const float* __restrict__ in,
                                 unsigned short* __restrict__ out, int n) {
  int total = n >> 2;
  int stride = gridDim.x * blockDim.x;
  for (int i = blockIdx.x * blockDim.x + threadIdx.x; i < total; i += stride) {
    float4 v = ((const float4*)in)[i];
    ushort4 o;
    o.x = f2bf(v.x); o.y = f2bf(v.y); o.z = f2bf(v.z); o.w = f2bf(v.w);
    ((ushort4*)out)[i] = o;
  }
}

// ---------------------------------------------------------------- cast + transpose
// in[K][N] fp32 -> out[N][K] bf16.  Lane along k => coalesced writes; float4
// streaming loads per lane (L1 catches the strided lines).
__global__ __launch_bounds__(256)
void castT_f32_bf16(const float* __restrict__ in, unsigned short* __restrict__ out,
                    int K, int N) {
  int k = blockIdx.x * 256 + threadIdx.x;
  int n0 = blockIdx.y * 128;
  const float* src = in + (size_t)k * N + n0;
  #pragma unroll 4
  for (int j4 = 0; j4 < 32; j4++) {
    float4 v = *(const float4*)&src[j4 * 4];
    out[(size_t)(n0 + j4 * 4 + 0) * K + k] = f2bf(v.x);
    out[(size_t)(n0 + j4 * 4 + 1) * K + k] = f2bf(v.y);
    out[(size_t)(n0 + j4 * 4 + 2) * K + k] = f2bf(v.z);
    out[(size_t)(n0 + j4 * 4 + 3) * K + k] = f2bf(v.w);
  }
}

// ---------------------------------------------------------------- QKV GEMM + RMS/RoPE
// qkv[M][9216] = x[M][3072] * w_qkvT[9216][3072]^T.  128x128 tile => each block's
// C-tile is one (type,head) x 128 seq rows.  1D grid 1152 with 8x8 supertile
// swizzle: XCD round-robin (lin%8) pins one bn per XCD per supertile -> w-reuse.
__global__ __launch_bounds__(256, 3)
void gemm_qkv(const unsigned short* __restrict__ A,
              const unsigned short* __restrict__ Bt,
              const float* __restrict__ pe,        // [L][64][2][2]
              const float* __restrict__ q_scale,
              const float* __restrict__ k_scale,
              unsigned short* __restrict__ Qo,     // [H][L][D]
              unsigned short* __restrict__ Ko,     // [H][L][D]
              unsigned short* __restrict__ Vo)     // [L][DIM]
{
  const int K = DIM_;
  __shared__ unsigned short As[128 * 64];
  __shared__ unsigned short Bs[128 * 64];
  const int tid  = threadIdx.x;
  const int wave = tid >> 6;
  const int lane = tid & 63;
  const int l15  = lane & 15;
  const int quad = lane >> 4;
  const int wm = wave >> 1, wn = wave & 1;

  // supertile decode: 8 bn x 8 bm per supertile of 64 blocks
  const int lin = blockIdx.x;
  const int st  = lin >> 6;
  const int w6  = lin & 63;
  const int bn_idx = (st >> 1) * 8 + (w6 & 7);    // 0..71
  const int bm_idx = (st & 1) * 8 + (w6 >> 3);    // 0..15
  const int bm = bm_idx * 128;
  const int bn = bn_idx * 128;

  const int srow = lane >> 3;
  const int scol = (lane & 7) ^ srow;
  const unsigned short* Ag = A  + (size_t)(bm + wave * 32 + srow) * K + scol * 8;
  const unsigned short* Bg = Bt + (size_t)(bn + wave * 32 + srow) * K + scol * 8;
  unsigned short* Al = &As[(wave * 32) * 64];
  unsigned short* Bl = &Bs[(wave * 32) * 64];

  f32x4 acc[4][4];
  #pragma unroll
  for (int i = 0; i < 4; i++)
    #pragma unroll
    for (int j = 0; j < 4; j++) acc[i][j] = (f32x4){0.f, 0.f, 0.f, 0.f};

  for (int k0 = 0; k0 < K; k0 += 64) {
    __syncthreads();
    #pragma unroll
    for (int j = 0; j < 4; j++) {
      gload_lds16(Ag + (size_t)j * 8 * K + k0, Al + j * 8 * 64);
      gload_lds16(Bg + (size_t)j * 8 * K + k0, Bl + j * 8 * 64);
    }
    __syncthreads();
    #pragma unroll
    for (int ks = 0; ks < 2; ks++) {
      const int cph = ((ks * 4 + quad) ^ (l15 & 7)) * 8;
      bf16x8 af[4], bf[4];
      #pragma unroll
      for (int mt = 0; mt < 4; mt++)
        af[mt] = *(const bf16x8*)&As[(wm * 64 + mt * 16 + l15) * 64 + cph];
      #pragma unroll
      for (int nt = 0; nt < 4; nt++)
        bf[nt] = *(const bf16x8*)&Bs[(wn * 64 + nt * 16 + l15) * 64 + cph];
      #pragma unroll
      for (int mt = 0; mt < 4; mt++)
        #pragma unroll
        for (int nt = 0; nt < 4; nt++)
          acc[mt][nt] = __builtin_amdgcn_mfma_f32_16x16x32_bf16(
              af[mt], bf[nt], acc[mt][nt], 0, 0, 0);
    }
  }
  __syncthreads();   // all waves done with As/Bs; safe to reuse As as rbuf

  if (bn_idx < 48) {
    // ---- q or k head: RMSNorm + RoPE on fp32 accumulators
    const bool isQ = bn_idx < 24;
    const int  hh  = isQ ? bn_idx : bn_idx - 24;
    const float* sc = isQ ? q_scale : k_scale;
    unsigned short* dst = isQ ? Qo : Ko;
    float* rbuf = (float*)As;                     // [2][128] partial sumsq
    #pragma unroll
    for (int mt = 0; mt < 4; mt++)
      #pragma unroll
      for (int r = 0; r < 4; r++) {
        float p = 0.f;
        #pragma unroll
        for (int nt = 0; nt < 4; nt++) p += acc[mt][nt][r] * acc[mt][nt][r];
        p += __shfl_xor(p, 1); p += __shfl_xor(p, 2);
        p += __shfl_xor(p, 4); p += __shfl_xor(p, 8);
        if (l15 == 0) rbuf[wn * 128 + wm * 64 + mt * 16 + quad * 4 + r] = p;
      }
    __syncthreads();
    #pragma unroll
    for (int mt = 0; mt < 4; mt++)
      #pragma unroll
      for (int r = 0; r < 4; r++) {
        const int lrow = wm * 64 + mt * 16 + quad * 4 + r;
        const int lg = bm + lrow;
        float ms = (rbuf[lrow] + rbuf[128 + lrow]) * (1.f / 128.f);
        float rinv = rsqrtf(ms + 1e-6f);
        #pragma unroll
        for (int nt = 0; nt < 4; nt++) {
          const int d = wn * 64 + nt * 16 + l15;
          float n  = acc[mt][nt][r] * rinv * sc[d];
          float np = __shfl_xor(n, 1);
          float2 ab = *(const float2*)&pe[(size_t)lg * 256 + (d >> 1) * 4 + (d & 1) * 2];
          float xe = (d & 1) ? np : n;
          float xo = (d & 1) ? n  : np;
          float o = ab.x * xe + ab.y * xo;
          if (isQ) o *= 0.08838834764831845f;     // 1/sqrt(128)
          dst[((size_t)hh * L_ + lg) * D_ + d] = f2bf(o);
        }
      }
  } else {
    // ---- v head: plain write to v_buf[L][DIM]
    const int hh = bn_idx - 48;
    #pragma unroll
    for (int mt = 0; mt < 4; mt++)
      #pragma unroll
      for (int nt = 0; nt < 4; nt++)
        #pragma unroll
        for (int r = 0; r < 4; r++) {
          int row = bm + wm * 64 + mt * 16 + quad * 4 + r;
          int col = hh * D_ + wn * 64 + nt * 16 + l15;
          Vo[(size_t)row * DIM_ + col] = f2bf(acc[mt][nt][r]);
        }
  }
}

// ---------------------------------------------------------------- proj GEMM, split-K=2
// partial[z][M][N] (fp32) = A[M][zK..] * Bt[N][zK..]^T over K/2.
__global__ __launch_bounds__(256, 3)
void gemm_proj_sk(const unsigned short* __restrict__ A,
                  const unsigned short* __restrict__ Bt,
                  float* __restrict__ P0, float* __restrict__ P1,
                  int M, int N, int K)
{
  __shared__ unsigned short As[128 * 64];
  __shared__ unsigned short Bs[128 * 64];
  const int tid  = threadIdx.x;
  const int wave = tid >> 6;
  const int lane = tid & 63;
  const int l15  = lane & 15;
  const int quad = lane >> 4;
  const int wm = wave >> 1, wn = wave & 1;
  const int bm = blockIdx.y * 128;
  const int bn = blockIdx.x * 128;
  const int z  = blockIdx.z;
  const int kbeg = z * (K >> 1), kend = kbeg + (K >> 1);
  float* Pout = z ? P1 : P0;

  const int srow = lane >> 3;
  const int scol = (lane & 7) ^ srow;
  const unsigned short* Ag = A  + (size_t)(bm + wave * 32 + srow) * K + scol * 8;
  const unsigned short* Bg = Bt + (size_t)(bn + wave * 32 + srow) * K + scol * 8;
  unsigned short* Al = &As[(wave * 32) * 64];
  unsigned short* Bl = &Bs[(wave * 32) * 64];

  f32x4 acc[4][4];
  #pragma unroll
  for (int i = 0; i < 4; i++)
    #pragma unroll
    for (int j = 0; j < 4; j++) acc[i][j] = (f32x4){0.f, 0.f, 0.f, 0.f};

  for (int k0 = kbeg; k0 < kend; k0 += 64) {
    __syncthreads();
    #pragma unroll
    for (int j = 0; j < 4; j++) {
      gload_lds16(Ag + (size_t)j * 8 * K + k0, Al + j * 8 * 64);
      gload_lds16(Bg + (size_t)j * 8 * K + k0, Bl + j * 8 * 64);
    }
    __syncthreads();
    #pragma unroll
    for (int ks = 0; ks < 2; ks++) {
      const int cph = ((ks * 4 + quad) ^ (l15 & 7)) * 8;
      bf16x8 af[4], bf[4];
      #pragma unroll
      for (int mt = 0; mt < 4; mt++)
        af[mt] = *(const bf16x8*)&As[(wm * 64 + mt * 16 + l15) * 64 + cph];
      #pragma unroll
      for (int nt = 0; nt < 4; nt++)
        bf[nt] = *(const bf16x8*)&Bs[(wn * 64 + nt * 16 + l15) * 64 + cph];
      #pragma unroll
      for (int mt = 0; mt < 4; mt++)
        #pragma unroll
        for (int nt = 0; nt < 4; nt++)
          acc[mt][nt] = __builtin_amdgcn_mfma_f32_16x16x32_bf16(
              af[mt], bf[nt], acc[mt][nt], 0, 0, 0);
    }
  }
  #pragma unroll
  for (int mt = 0; mt < 4; mt++)
    #pragma unroll
    for (int nt = 0; nt < 4; nt++)
      #pragma unroll
      for (int r = 0; r < 4; r++) {
        int row = bm + wm * 64 + mt * 16 + quad * 4 + r;
        int col = bn + wn * 64 + nt * 16 + l15;
        Pout[(size_t)row * N + col] = acc[mt][nt][r];
      }
}

// ---------------------------------------------------------------- reduce + bias
// out[row][col] = p0 + p1 + bias[col].  grid (3, 2048): 768 float4/row.
__global__ __launch_bounds__(256)
void reduce_bias(const float* __restrict__ p0, const float* __restrict__ p1,
                 const float* __restrict__ bias, float* __restrict__ out)
{
  int col4 = blockIdx.x * 256 + threadIdx.x;      // 0..767
  size_t idx = (size_t)blockIdx.y * 768 + col4;
  float4 a = ((const float4*)p0)[idx];
  float4 b = ((const float4*)p1)[idx];
  float4 c = ((const float4*)bias)[col4];
  float4 o = make_float4(a.x + b.x + c.x, a.y + b.y + c.y,
                         a.z + b.z + c.z, a.w + b.w + c.w);
  ((float4*)out)[idx] = o;
}

// ---------------------------------------------------------------- V transpose
// v_buf[l][h*128+d] -> Vt[h][d][l].  Lane = l: coalesced writes along Vt rows.
__global__ __launch_bounds__(256)
void v_transpose(const unsigned short* __restrict__ v_buf,
                 unsigned short* __restrict__ Vt) {
  int h = blockIdx.y;
  int l = blockIdx.x * 256 + threadIdx.x;
  const unsigned short* src = v_buf + (size_t)l * DIM_ + h * D_;
  unsigned short* dst = Vt + (size_t)h * D_ * L_ + l;
  #pragma unroll
  for (int c = 0; c < 16; c++) {
    uint4 v = *(const uint4*)&src[c * 8];
    const unsigned short* pv = (const unsigned short*)&v;
    #pragma unroll
    for (int j = 0; j < 8; j++)
      dst[(size_t)(c * 8 + j) * L_] = pv[j];
  }
}

// ---------------------------------------------------------------- flash attention
// Block: 4 waves, 64 queries, one head. Wave = (qg, kh): q-group of 32,
// key-half of the shared 64-key tile. S^T = K*Q^T so softmax is lane-indexed
// (q = l15) and P stays in registers as A-frags for mfma_16x16x16 PV.
__global__ __launch_bounds__(256, 3)
void flash_attn(const unsigned short* __restrict__ Q,   // [H][L][D]
                const unsigned short* __restrict__ K,   // [H][L][D]
                const unsigned short* __restrict__ Vt,  // [H][D][L]
                unsigned short* __restrict__ Out)       // [L][DIM]
{
  __shared__ __align__(16) char smem[34304];
  unsigned short* Ks = (unsigned short*)smem;          // [64][128] swizzled(16)
  unsigned short* Vs = Ks + 8192;                      // [128][64] swizzled(8)
  float*  Obuf = (float*)smem;                         // merge: [2][32][128]
  float2* mlb  = (float2*)(smem + 32768);              // [2*32]
  float4* sAr  = (float4*)(smem + 33280);              // [2*32]

  const int tid  = threadIdx.x;
  const int wave = tid >> 6;
  const int lane = tid & 63;
  const int l15  = lane & 15;
  const int quad = lane >> 4;
  const int qg = wave >> 1;
  const int kh = wave & 1;
  const int h  = blockIdx.y;
  const int q0 = blockIdx.x * 64 + qg * 32;

  const unsigned short* Qh = Q  + (size_t)h * L_ * D_;
  const unsigned short* Kh = K  + (size_t)h * L_ * D_;
  const unsigned short* Vh = Vt + (size_t)h * D_ * L_;

  bf16x8 qf[2][4];
  #pragma unroll
  for (int nt = 0; nt < 2; nt++)
    #pragma unroll
    for (int kc = 0; kc < 4; kc++)
      qf[nt][kc] = *(const bf16x8*)&Qh[(size_t)(q0 + nt * 16 + l15) * D_ + kc * 32 + quad * 8];

  f32x4 oacc[2][8];
  #pragma unroll
  for (int i = 0; i < 2; i++)
    #pragma unroll
    for (int j = 0; j < 8; j++) oacc[i][j] = (f32x4){0.f, 0.f, 0.f, 0.f};
  float m_i[2] = {-1e30f, -1e30f}, l_i[2] = {0.f, 0.f};

  const int kr_l = lane >> 4;
  const int vr_l = lane >> 3;
  const int vcl  = (lane & 7) ^ vr_l;

  for (int t = 0; t < L_; t += 64) {
    __syncthreads();
    #pragma unroll
    for (int ji = 0; ji < 4; ji++) {
      int Rr = wave * 16 + ji * 4;
      int cl = (lane & 15) ^ ((Rr + kr_l) & 15);
      gload_lds16(&Kh[(size_t)(t + Rr + kr_l) * D_ + cl * 8], &Ks[Rr * 128]);
      int R2 = wave * 32 + ji * 8;
      gload_lds16(&Vh[(size_t)(R2 + vr_l) * L_ + t + vcl * 8], &Vs[R2 * 64]);
    }
    __syncthreads();

    f32x4 s[2][2];
    #pragma unroll
    for (int i = 0; i < 2; i++)
      #pragma unroll
      for (int j = 0; j < 2; j++) s[i][j] = (f32x4){0.f, 0.f, 0.f, 0.f};
    #pragma unroll
    for (int mt = 0; mt < 2; mt++) {
      const int krow = kh * 32 + mt * 16 + l15;
      #pragma unroll
      for (int kc = 0; kc < 4; kc++) {
        bf16x8 kf = *(const bf16x8*)&Ks[krow * 128 + (((kc * 4 + quad) ^ l15) * 8)];
        s[mt][0] = __builtin_amdgcn_mfma_f32_16x16x32_bf16(kf, qf[0][kc], s[mt][0], 0, 0, 0);
        s[mt][1] = __builtin_amdgcn_mfma_f32_16x16x32_bf16(kf, qf[1][kc], s[mt][1], 0, 0, 0);
      }
    }
    float vmax[2], alpha[2], rs[2];
    #pragma unroll
    for (int nt = 0; nt < 2; nt++) {
      vmax[nt] = fmaxf(fmaxf(fmaxf(s[0][nt][0], s[0][nt][1]), fmaxf(s[0][nt][2], s[0][nt][3])),
                       fmaxf(fmaxf(s[1][nt][0], s[1][nt][1]), fmaxf(s[1][nt][2], s[1][nt][3])));
      vmax[nt] = fmaxf(vmax[nt], __shfl_xor(vmax[nt], 16));
      vmax[nt] = fmaxf(vmax[nt], __shfl_xor(vmax[nt], 32));
      float mnew = fmaxf(m_i[nt], vmax[nt]);
      alpha[nt] = __expf(m_i[nt] - mnew);
      m_i[nt] = mnew;
      rs[nt] = 0.f;
    }
    #pragma unroll
    for (int mt = 0; mt < 2; mt++)
      #pragma unroll
      for (int nt = 0; nt < 2; nt++)
        #pragma unroll
        for (int r = 0; r < 4; r++) {
          float p = __expf(s[mt][nt][r] - m_i[nt]);
          s[mt][nt][r] = p;
          rs[nt] += p;
        }
    #pragma unroll
    for (int nt = 0; nt < 2; nt++) {
      rs[nt] += __shfl_xor(rs[nt], 16);
      rs[nt] += __shfl_xor(rs[nt], 32);
      l_i[nt] = l_i[nt] * alpha[nt] + rs[nt];
    }
    float ar[2][4];
    #pragma unroll
    for (int qt = 0; qt < 2; qt++)
      #pragma unroll
      for (int r = 0; r < 4; r++)
        ar[qt][r] = __shfl(alpha[qt], quad * 4 + r);
    #pragma unroll
    for (int qt = 0; qt < 2; qt++)
      #pragma unroll
      for (int ntd = 0; ntd < 8; ntd++)
        #pragma unroll
        for (int r = 0; r < 4; r++)
          oacc[qt][ntd][r] *= ar[qt][r];
    bf16x4 pk[2][2];
    #pragma unroll
    for (int mt = 0; mt < 2; mt++)
      #pragma unroll
      for (int qt = 0; qt < 2; qt++)
        pk[mt][qt] = (bf16x4){(short)f2bf(s[mt][qt][0]), (short)f2bf(s[mt][qt][1]),
                              (short)f2bf(s[mt][qt][2]), (short)f2bf(s[mt][qt][3])};
    #pragma unroll
    for (int ntd = 0; ntd < 8; ntd++) {
      const int vrow = ntd * 16 + l15;
      #pragma unroll
      for (int mt = 0; mt < 2; mt++) {
        int phys = (kh * 4 + mt * 2 + (quad >> 1)) ^ (l15 & 7);
        bf16x4 vf = *(const bf16x4*)&Vs[vrow * 64 + phys * 8 + (quad & 1) * 4];
        oacc[0][ntd] = __builtin_amdgcn_mfma_f32_16x16x16bf16_1k(pk[mt][0], vf, oacc[0][ntd], 0, 0, 0);
        oacc[1][ntd] = __builtin_amdgcn_mfma_f32_16x16x16bf16_1k(pk[mt][1], vf, oacc[1][ntd], 0, 0, 0);
      }
    }
  }

  __syncthreads();
  if (kh == 1) {
    #pragma unroll
    for (int qt = 0; qt < 2; qt++)
      #pragma unroll
      for (int ntd = 0; ntd < 8; ntd++)
        #pragma unroll
        for (int r = 0; r < 4; r++)
          Obuf[(size_t)(qg * 32 + qt * 16 + quad * 4 + r) * 128 + ntd * 16 + l15] = oacc[qt][ntd][r];
    if (quad == 0)
      #pragma unroll
      for (int qt = 0; qt < 2; qt++)
        mlb[qg * 32 + qt * 16 + l15] = make_float2(m_i[qt], l_i[qt]);
  }
  __syncthreads();
  if (kh == 0 && quad == 0) {
    #pragma unroll
    for (int qt = 0; qt < 2; qt++) {
      float2 m1 = mlb[qg * 32 + qt * 16 + l15];
      float M  = fmaxf(m_i[qt], m1.x);
      float a0 = __expf(m_i[qt] - M);
      float a1 = __expf(m1.x - M);
      float Ls = l_i[qt] * a0 + m1.y * a1;
      sAr[qg * 32 + qt * 16 + l15] = make_float4(a0, a1, 1.f / Ls, 0.f);
    }
  }
  __syncthreads();
  if (kh == 0) {
    #pragma unroll
    for (int qt = 0; qt < 2; qt++)
      #pragma unroll
      for (int r = 0; r < 4; r++) {
        float4 A = sAr[qg * 32 + qt * 16 + quad * 4 + r];
        #pragma unroll
        for (int ntd = 0; ntd < 8; ntd++) {
          float o1 = Obuf[(size_t)(qg * 32 + qt * 16 + quad * 4 + r) * 128 + ntd * 16 + l15];
          float v  = (oacc[qt][ntd][r] * A.x + o1 * A.y) * A.z;
          Out[(size_t)(q0 + qt * 16 + quad * 4 + r) * DIM_ + h * D_ + ntd * 16 + l15] = f2bf(v);
        }
      }
  }
}

// ---------------------------------------------------------------- launcher
extern "C" void kernel_launch(void* const* d_in, const int* in_sizes, int n_in,
                              void* d_out, int out_size, void* d_ws, size_t ws_size,
                              hipStream_t stream) {
  const float* x       = (const float*)d_in[0];
  const float* pe      = (const float*)d_in[1];
  const float* w_qkv   = (const float*)d_in[2];
  const float* q_scale = (const float*)d_in[3];
  const float* k_scale = (const float*)d_in[4];
  const float* w_proj  = (const float*)d_in[5];
  const float* b_proj  = (const float*)d_in[6];

  unsigned short* w_qkvT  = (unsigned short*)d_ws;           // [9216][3072]
  unsigned short* w_projT = w_qkvT + 28311552;               // [3072][3072]
  unsigned short* x_b     = w_projT + 9437184;               // [2048][3072]
  unsigned short* v_buf   = x_b + 6291456;                   // [2048][3072]
  unsigned short* q_r     = v_buf + 6291456;                 // [H][L][D]
  unsigned short* k_r     = q_r + 6291456;
  unsigned short* vt_r    = k_r + 6291456;                   // [H][D][L]
  unsigned short* attn_b  = vt_r + 6291456;                  // [L][DIM]
  // split-K partials reuse dead bf16 buffers (each pair = exactly 25.17 MB):
  float* proj_p0 = (float*)x_b;   // x_b+v_buf dead after v_transpose
  float* proj_p1 = (float*)q_r;   // q_r+k_r dead after flash_attn

  cast_f32_to_bf16<<<2048, 256, 0, stream>>>(x, x_b, 6291456);
  castT_f32_bf16<<<dim3(12, 72), 256, 0, stream>>>(w_qkv, w_qkvT, 3072, 9216);
  castT_f32_bf16<<<dim3(12, 24), 256, 0, stream>>>(w_proj, w_projT, 3072, 3072);

  gemm_qkv<<<1152, 256, 0, stream>>>(
      x_b, w_qkvT, pe, q_scale, k_scale, q_r, k_r, v_buf);

  v_transpose<<<dim3(8, 24), 256, 0, stream>>>(v_buf, vt_r);

  flash_attn<<<dim3(32, 24), 256, 0, stream>>>(q_r, k_r, vt_r, attn_b);

  gemm_proj_sk<<<dim3(24, 16, 2), 256, 0, stream>>>(
      attn_b, w_projT, proj_p0, proj_p1, 2048, 3072, 3072);

  reduce_bias<<<dim3(3, 2048), 256, 0, stream>>>(
      proj_p0, proj_p1, b_proj, (float*)d_out);
}